// Round 17
// baseline (247.062 us; speedup 1.0000x reference)
//
#include <hip/hip_runtime.h>
#include <cstdint>
#include <cstddef>

#define GG 512
#define NF 64
#define EPSF 1e-5f

__device__ __forceinline__ void atomAddF(float* p, float v) {
    unsafeAtomicAdd(p, v);   // hardware global_atomic_add_f32
}

// ---------------- Pass A: per-graph sum / sumsq / count of x00 ----------------
__global__ __launch_bounds__(256) void k_stats(const float* __restrict__ x00, const int* __restrict__ gid,
                        float* __restrict__ gsum, float* __restrict__ gsq,
                        float* __restrict__ gcnt, int N)
{
    int w = (blockIdx.x * blockDim.x + threadIdx.x) >> 6;
    int lane = threadIdx.x & 63;
    long base = (long)w * 64;
    int gf = gid[base];
    int gl = gid[base + 63];
    if (gf == gl) {
        const float4* p = reinterpret_cast<const float4*>(x00 + base * NF) + lane;
        float s0=0,s1=0,s2=0,s3=0,q0=0,q1=0,q2=0,q3=0;
        #pragma unroll
        for (int k = 0; k < 16; ++k) {
            float4 v = p[k * 64];
            s0+=v.x; s1+=v.y; s2+=v.z; s3+=v.w;
            q0=fmaf(v.x,v.x,q0); q1=fmaf(v.y,v.y,q1); q2=fmaf(v.z,v.z,q2); q3=fmaf(v.w,v.w,q3);
        }
        #pragma unroll
        for (int m = 16; m < 64; m <<= 1) {
            s0+=__shfl_xor(s0,m); s1+=__shfl_xor(s1,m); s2+=__shfl_xor(s2,m); s3+=__shfl_xor(s3,m);
            q0+=__shfl_xor(q0,m); q1+=__shfl_xor(q1,m); q2+=__shfl_xor(q2,m); q3+=__shfl_xor(q3,m);
        }
        if (lane < 16) {
            float* ds = gsum + gf * NF + lane * 4;
            float* dq = gsq  + gf * NF + lane * 4;
            atomAddF(ds+0,s0); atomAddF(ds+1,s1); atomAddF(ds+2,s2); atomAddF(ds+3,s3);
            atomAddF(dq+0,q0); atomAddF(dq+1,q1); atomAddF(dq+2,q2); atomAddF(dq+3,q3);
        }
        if (lane == 0) atomAddF(&gcnt[gf], 64.0f);
    } else {
        int myg = gid[base + lane];
        int cur = gf;
        float s = 0.f, q = 0.f, cnt = 0.f;
        for (int k = 0; k < 64; ++k) {
            int g = __shfl(myg, k);
            if (g != cur) {
                atomAddF(&gsum[cur * NF + lane], s);
                atomAddF(&gsq [cur * NF + lane], q);
                if (lane == 0) atomAddF(&gcnt[cur], cnt);
                s = q = cnt = 0.f; cur = g;
            }
            float v = x00[(base + k) * NF + lane];
            s += v; q = fmaf(v, v, q); cnt += 1.f;
        }
        atomAddF(&gsum[cur * NF + lane], s);
        atomAddF(&gsq [cur * NF + lane], q);
        if (lane == 0) atomAddF(&gcnt[cur], cnt);
    }
}

// ------------- Per-graph effective affine weights for logits ------------------
__global__ void k_prep(const float* __restrict__ gsum, const float* __restrict__ gsq,
                       const float* __restrict__ gcnt,
                       const float* __restrict__ gamma, const float* __restrict__ beta,
                       const float* __restrict__ lin_w, const float* __restrict__ lin_b,
                       float* __restrict__ Aeff, float* __restrict__ Beff)
{
    int g = blockIdx.x;
    int c = threadIdx.x;           // 64 threads = 1 wave
    float cnt = fmaxf(gcnt[g], 1.f);
    float mean = gsum[g * NF + c] / cnt;
    float var  = gsq [g * NF + c] / cnt - mean * mean;
    float rs = rsqrtf(var + EPSF);
    float ga = gamma[c], be = beta[c];
    #pragma unroll
    for (int j = 0; j < 3; ++j) {
        float wv = lin_w[j * NF + c];
        Aeff[((long)g * 3 + j) * NF + c] = rs * ga * wv;
        float term = (be - mean * rs * ga) * wv;
        #pragma unroll
        for (int m = 32; m; m >>= 1) term += __shfl_xor(term, m);
        if (c == 0) Beff[g * 3 + j] = term + lin_b[j];
    }
}

// --------- Pass B: logits -> e (no max-shift), pos-weighted sums, e-sums ------
__global__ __launch_bounds__(128) void k_logits(const float* __restrict__ x00, const int* __restrict__ gid,
                         const float* __restrict__ pos,
                         const float* __restrict__ Aeff, const float* __restrict__ Beff,
                         float* __restrict__ ebp, float* __restrict__ accum, int N)
{
    __shared__ float T2[2][64 * 68];
    int wid = threadIdx.x >> 6;
    int lane = threadIdx.x & 63;
    long chunk = (long)blockIdx.x * 2 + wid;
    long base = chunk * 64;
    float* T = T2[wid];

    const float* src = x00 + base * NF;
    #pragma unroll
    for (int k = 0; k < 16; ++k) {
        int fl = k * 256 + lane * 4;
        float4 v = *reinterpret_cast<const float4*>(src + fl);
        int n = fl >> 6, c = fl & 63;
        *reinterpret_cast<float4*>(&T[n * 68 + c]) = v;
    }
    __syncthreads();

    int gf = gid[base], gl = gid[base + 63];
    float l0, l1, l2;
    int g_l;
    if (gf == gl) {
        g_l = gf;
        const float* ap = Aeff + (size_t)gf * 192;
        float a0a=0,a0b=0,a1a=0,a1b=0,a2a=0,a2b=0;
        #pragma unroll
        for (int t = 0; t < 16; ++t) {
            float4 xv = *reinterpret_cast<const float4*>(&T[lane * 68 + 4 * t]);
            float4 w0 = *reinterpret_cast<const float4*>(ap + 4 * t);
            float4 w1 = *reinterpret_cast<const float4*>(ap + 64 + 4 * t);
            float4 w2 = *reinterpret_cast<const float4*>(ap + 128 + 4 * t);
            a0a = fmaf(xv.x,w0.x,fmaf(xv.y,w0.y,a0a)); a0b = fmaf(xv.z,w0.z,fmaf(xv.w,w0.w,a0b));
            a1a = fmaf(xv.x,w1.x,fmaf(xv.y,w1.y,a1a)); a1b = fmaf(xv.z,w1.z,fmaf(xv.w,w1.w,a1b));
            a2a = fmaf(xv.x,w2.x,fmaf(xv.y,w2.y,a2a)); a2b = fmaf(xv.z,w2.z,fmaf(xv.w,w2.w,a2b));
        }
        l0 = a0a + a0b + Beff[gf*3+0];
        l1 = a1a + a1b + Beff[gf*3+1];
        l2 = a2a + a2b + Beff[gf*3+2];
    } else {
        g_l = gid[base + lane];
        const float* ap = Aeff + (size_t)g_l * 192;
        float a0=0,a1=0,a2=0;
        #pragma unroll
        for (int t = 0; t < 16; ++t) {
            float4 xv = *reinterpret_cast<const float4*>(&T[lane * 68 + 4 * t]);
            float4 w0 = *reinterpret_cast<const float4*>(ap + 4 * t);
            float4 w1 = *reinterpret_cast<const float4*>(ap + 64 + 4 * t);
            float4 w2 = *reinterpret_cast<const float4*>(ap + 128 + 4 * t);
            a0 = fmaf(xv.x,w0.x,fmaf(xv.y,w0.y,fmaf(xv.z,w0.z,fmaf(xv.w,w0.w,a0))));
            a1 = fmaf(xv.x,w1.x,fmaf(xv.y,w1.y,fmaf(xv.z,w1.z,fmaf(xv.w,w1.w,a1))));
            a2 = fmaf(xv.x,w2.x,fmaf(xv.y,w2.y,fmaf(xv.z,w2.z,fmaf(xv.w,w2.w,a2))));
        }
        l0 = a0 + Beff[g_l*3+0];
        l1 = a1 + Beff[g_l*3+1];
        l2 = a2 + Beff[g_l*3+2];
    }
    float e0 = expf(l0), e1 = expf(l1), e2 = expf(l2);
    long node = base + lane;
    ebp[node]            = e0;
    ebp[(long)N + node]  = e1;

    const float* pp = pos + node * 6;
    float2 v01 = *reinterpret_cast<const float2*>(pp);
    float2 v23 = *reinterpret_cast<const float2*>(pp + 2);
    float2 v45 = *reinterpret_cast<const float2*>(pp + 4);
    float p0 = v01.x*e2, p1 = v01.y*e2, p2 = v23.x*e2, p3 = v23.y*e2, p4 = v45.x*e2, p5 = v45.y*e2;
    if (gf == gl) {
        #pragma unroll
        for (int m = 1; m < 64; m <<= 1) {
            e0+=__shfl_xor(e0,m); e1+=__shfl_xor(e1,m); e2+=__shfl_xor(e2,m);
            p0+=__shfl_xor(p0,m); p1+=__shfl_xor(p1,m); p2+=__shfl_xor(p2,m);
            p3+=__shfl_xor(p3,m); p4+=__shfl_xor(p4,m); p5+=__shfl_xor(p5,m);
        }
        if (lane == 0) {
            float* dst = accum + (long)gf * 32;
            atomAddF(dst+16,p0); atomAddF(dst+17,p1); atomAddF(dst+18,p2);
            atomAddF(dst+19,p3); atomAddF(dst+20,p4); atomAddF(dst+21,p5);
            atomAddF(dst+22,e0); atomAddF(dst+23,e1); atomAddF(dst+24,e2);
        }
    } else {
        float* dst = accum + (long)g_l * 32;
        atomAddF(dst+16,p0); atomAddF(dst+17,p1); atomAddF(dst+18,p2);
        atomAddF(dst+19,p3); atomAddF(dst+20,p4); atomAddF(dst+21,p5);
        atomAddF(dst+22,e0); atomAddF(dst+23,e1); atomAddF(dst+24,e2);
    }
}

// ---- Pass D (merged): DENSE per-wave float4 bursts consumed from registers.
// Rotation trick: for flat idx f = 4*lane + 256*j + k, d = f mod 9 (or 3) is
// a per-lane rotation r of a COMPILE-TIME slot s. Accumulate z[s] in registers,
// un-rotate only at flush (per-wave LDS scatter + column sum, NO barriers).
__global__ __launch_bounds__(256, 4) void k_wsum(const float* __restrict__ x10,
        const float* __restrict__ x01, const float* __restrict__ x11,
        const float* __restrict__ ebp, const int* __restrict__ gid,
        const float* __restrict__ w10, const float* __restrict__ w01,
        const float* __restrict__ w11, float* __restrict__ accum, int N)
{
    __shared__ float LDSW[4][576];
    const int tid = threadIdx.x;
    const int wid = tid >> 6;
    const int lane = tid & 63;
    float* L = LDSW[wid];

    if ((blockIdx.x & 1) == 0) {
        // ================= x11: 64-node chunk per wave =================
        const long base = ((long)(blockIdx.x >> 1) * 4 + wid) * 64;
        const float e_regf = ebp[base + lane];
        const int   g_reg  = gid[base + lane];

        // per-lane precompute: node, rotation, weights
        int nj[9]; float wvx[9], wvy[9], wvz[9], wvw[9];
        #pragma unroll
        for (int j = 0; j < 9; ++j) {
            int f0 = 4 * (lane + 64 * j);
            nj[j] = (f0 % 2304) / 144;      // f0 < 2304 always
            int rem = f0 % 144;
            wvx[j] = w11[(rem + 0) / 9];
            wvy[j] = w11[(rem + 1) / 9];
            wvz[j] = w11[(rem + 2) / 9];
            wvw[j] = w11[(rem + 3) / 9];
        }
        const int r = (4 * lane) % 9;
        int rot[9];
        #pragma unroll
        for (int s = 0; s < 9; ++s) rot[s] = (r + s) % 9;

        float z[9];
        #pragma unroll
        for (int s = 0; s < 9; ++s) z[s] = 0.f;
        int cur = __shfl(g_reg, 0);
        bool dirty = false;

        auto flushZ = [&](int g) {
            if (!dirty) return;
            #pragma unroll
            for (int s = 0; s < 9; ++s) L[lane * 9 + rot[s]] = z[s];
            asm volatile("s_waitcnt lgkmcnt(0)" ::: "memory");
            __builtin_amdgcn_sched_barrier(0);
            if (lane < 9) {
                float sum = 0.f;
                for (int m = 0; m < 64; ++m) sum += L[m * 9 + lane];
                atomAddF(accum + (long)g * 32 + 6 + lane, sum);
            }
            asm volatile("s_waitcnt lgkmcnt(0) vmcnt(0)" ::: "memory");
            #pragma unroll
            for (int s = 0; s < 9; ++s) z[s] = 0.f;
            dirty = false;
        };

        #define X11ACC(J) do { \
            const float en = __shfl(e_regf, t16 + nj[J]); \
            z[(4*(J)+0)%9] = fmaf(en * wvx[J], B##J.x, z[(4*(J)+0)%9]); \
            z[(4*(J)+1)%9] = fmaf(en * wvy[J], B##J.y, z[(4*(J)+1)%9]); \
            z[(4*(J)+2)%9] = fmaf(en * wvz[J], B##J.z, z[(4*(J)+2)%9]); \
            z[(4*(J)+3)%9] = fmaf(en * wvw[J], B##J.w, z[(4*(J)+3)%9]); \
        } while (0)

        #define X11ATOM(J) do { \
            const int nn = t16 + nj[J]; \
            const float en = __shfl(e_regf, nn); \
            const int   gg = __shfl(g_reg,  nn); \
            float* dst = accum + (long)gg * 32 + 6; \
            atomAddF(dst + rot[(4*(J)+0)%9], en * wvx[J] * B##J.x); \
            atomAddF(dst + rot[(4*(J)+1)%9], en * wvy[J] * B##J.y); \
            atomAddF(dst + rot[(4*(J)+2)%9], en * wvz[J] * B##J.z); \
            atomAddF(dst + rot[(4*(J)+3)%9], en * wvw[J] * B##J.w); \
        } while (0)

        for (int t = 0; t < 4; ++t) {
            const int t16 = t * 16;
            const float4* s4 = reinterpret_cast<const float4*>(x11 + (base + t16) * 144);
            float4 B0 = s4[lane];
            float4 B1 = s4[lane + 64];
            float4 B2 = s4[lane + 128];
            float4 B3 = s4[lane + 192];
            float4 B4 = s4[lane + 256];
            float4 B5 = s4[lane + 320];
            float4 B6 = s4[lane + 384];
            float4 B7 = s4[lane + 448];
            float4 B8 = s4[lane + 512];
            int gft = __shfl(g_reg, t16), glt = __shfl(g_reg, t16 + 15);
            if (gft == glt) {
                if (gft != cur) { flushZ(cur); cur = gft; }
                X11ACC(0); X11ACC(1); X11ACC(2); X11ACC(3); X11ACC(4);
                X11ACC(5); X11ACC(6); X11ACC(7); X11ACC(8);
                dirty = true;
            } else {
                flushZ(cur);
                X11ATOM(0); X11ATOM(1); X11ATOM(2); X11ATOM(3); X11ATOM(4);
                X11ATOM(5); X11ATOM(6); X11ATOM(7); X11ATOM(8);
                cur = glt;
            }
        }
        flushZ(cur);
    } else {
        // ================= x10 & x01: 64-node chunk per wave =================
        const long base = ((long)(blockIdx.x >> 1) * 4 + wid) * 64;
        const float e_regf = ebp[(long)N + base + lane];
        const int   g_reg  = gid[base + lane];

        int nj[3]; float axx[3], axy[3], axz[3], axw[3], bxx[3], bxy[3], bxz[3], bxw[3];
        #pragma unroll
        for (int j = 0; j < 3; ++j) {
            int f0 = 4 * (lane + 64 * j);
            nj[j] = f0 / 48;                 // f0 < 768
            int rem = f0 % 48;
            axx[j] = w10[(rem + 0) / 3]; axy[j] = w10[(rem + 1) / 3];
            axz[j] = w10[(rem + 2) / 3]; axw[j] = w10[(rem + 3) / 3];
            bxx[j] = w01[(rem + 0) / 3]; bxy[j] = w01[(rem + 1) / 3];
            bxz[j] = w01[(rem + 2) / 3]; bxw[j] = w01[(rem + 3) / 3];
        }
        const int r3 = lane % 3;
        int rot3[3];
        #pragma unroll
        for (int s = 0; s < 3; ++s) rot3[s] = (r3 + s) % 3;

        float zA[3], zB[3];
        #pragma unroll
        for (int s = 0; s < 3; ++s) { zA[s] = 0.f; zB[s] = 0.f; }
        int cur = __shfl(g_reg, 0);
        bool dirty = false;

        auto flushZ = [&](int g) {
            if (!dirty) return;
            #pragma unroll
            for (int s = 0; s < 3; ++s) {
                L[lane * 6 + rot3[s]]     = zA[s];
                L[lane * 6 + 3 + rot3[s]] = zB[s];
            }
            asm volatile("s_waitcnt lgkmcnt(0)" ::: "memory");
            __builtin_amdgcn_sched_barrier(0);
            if (lane < 6) {
                float sum = 0.f;
                for (int m = 0; m < 64; ++m) sum += L[m * 6 + lane];
                atomAddF(accum + (long)g * 32 + lane, sum);   // [0..2]=x10, [3..5]=x01
            }
            asm volatile("s_waitcnt lgkmcnt(0) vmcnt(0)" ::: "memory");
            #pragma unroll
            for (int s = 0; s < 3; ++s) { zA[s] = 0.f; zB[s] = 0.f; }
            dirty = false;
        };

        #define XABACC(J) do { \
            const float en = __shfl(e_regf, t16 + nj[J]); \
            zA[((J)+0)%3] = fmaf(en * axx[J], A##J.x, zA[((J)+0)%3]); \
            zA[((J)+1)%3] = fmaf(en * axy[J], A##J.y, zA[((J)+1)%3]); \
            zA[((J)+2)%3] = fmaf(en * axz[J], A##J.z, zA[((J)+2)%3]); \
            zA[((J)+3)%3] = fmaf(en * axw[J], A##J.w, zA[((J)+3)%3]); \
            zB[((J)+0)%3] = fmaf(en * bxx[J], C##J.x, zB[((J)+0)%3]); \
            zB[((J)+1)%3] = fmaf(en * bxy[J], C##J.y, zB[((J)+1)%3]); \
            zB[((J)+2)%3] = fmaf(en * bxz[J], C##J.z, zB[((J)+2)%3]); \
            zB[((J)+3)%3] = fmaf(en * bxw[J], C##J.w, zB[((J)+3)%3]); \
        } while (0)

        #define XABATOM(J) do { \
            const int nn = t16 + nj[J]; \
            const float en = __shfl(e_regf, nn); \
            const int   gg = __shfl(g_reg,  nn); \
            float* dst = accum + (long)gg * 32; \
            atomAddF(dst + rot3[((J)+0)%3], en * axx[J] * A##J.x); \
            atomAddF(dst + rot3[((J)+1)%3], en * axy[J] * A##J.y); \
            atomAddF(dst + rot3[((J)+2)%3], en * axz[J] * A##J.z); \
            atomAddF(dst + rot3[((J)+3)%3], en * axw[J] * A##J.w); \
            atomAddF(dst + 3 + rot3[((J)+0)%3], en * bxx[J] * C##J.x); \
            atomAddF(dst + 3 + rot3[((J)+1)%3], en * bxy[J] * C##J.y); \
            atomAddF(dst + 3 + rot3[((J)+2)%3], en * bxz[J] * C##J.z); \
            atomAddF(dst + 3 + rot3[((J)+3)%3], en * bxw[J] * C##J.w); \
        } while (0)

        for (int t = 0; t < 4; ++t) {
            const int t16 = t * 16;
            const float4* sa = reinterpret_cast<const float4*>(x10 + (base + t16) * 48);
            const float4* sb = reinterpret_cast<const float4*>(x01 + (base + t16) * 48);
            float4 A0 = sa[lane];
            float4 A1 = sa[lane + 64];
            float4 A2 = sa[lane + 128];
            float4 C0 = sb[lane];
            float4 C1 = sb[lane + 64];
            float4 C2 = sb[lane + 128];
            int gft = __shfl(g_reg, t16), glt = __shfl(g_reg, t16 + 15);
            if (gft == glt) {
                if (gft != cur) { flushZ(cur); cur = gft; }
                XABACC(0); XABACC(1); XABACC(2);
                dirty = true;
            } else {
                flushZ(cur);
                XABATOM(0); XABATOM(1); XABATOM(2);
                cur = glt;
            }
        }
        flushZ(cur);
    }
}

// --------------------------- Pass E: per-graph epilogue -----------------------
#define JROT(p, q) do { \
    float apq_ = S[p][q]; \
    if (fabsf(apq_) > 1e-20f) { \
        float app_ = S[p][p], aqq_ = S[q][q]; \
        float tau_ = (aqq_ - app_) / (2.0f * apq_); \
        float tt_ = copysignf(1.0f, tau_) / (fabsf(tau_) + sqrtf(1.0f + tau_ * tau_)); \
        float cc_ = 1.0f / sqrtf(1.0f + tt_ * tt_); \
        float ssn_ = tt_ * cc_; \
        _Pragma("unroll") for (int kk = 0; kk < 3; ++kk) { \
            float skp = S[kk][p], skq = S[kk][q]; \
            S[kk][p] = cc_ * skp - ssn_ * skq; S[kk][q] = ssn_ * skp + cc_ * skq; } \
        _Pragma("unroll") for (int kk = 0; kk < 3; ++kk) { \
            float spk = S[p][kk], sqk = S[q][kk]; \
            S[p][kk] = cc_ * spk - ssn_ * sqk; S[q][kk] = ssn_ * spk + cc_ * sqk; } \
        _Pragma("unroll") for (int kk = 0; kk < 3; ++kk) { \
            float vkp = V[kk][p], vkq = V[kk][q]; \
            V[kk][p] = cc_ * vkp - ssn_ * vkq; V[kk][q] = ssn_ * vkp + cc_ * vkq; } \
    } \
} while (0)

__global__ void k_final(const float* __restrict__ accum, float* __restrict__ out)
{
    int g = blockIdx.x * blockDim.x + threadIdx.x;
    if (g >= GG) return;
    const float* A_ = accum + (long)g * 32;
    float i0 = 1.f / A_[22], i1 = 1.f / A_[23], i2 = 1.f / A_[24];

    float o10[3], o01[3], o11[9];
    #pragma unroll
    for (int d = 0; d < 3; ++d) { o10[d] = A_[d] * i1; o01[d] = A_[3 + d] * i1; }
    #pragma unroll
    for (int d = 0; d < 9; ++d) o11[d] = A_[6 + d] * i0;

    float m1v[3], m2v[3];
    #pragma unroll
    for (int d = 0; d < 3; ++d) { m1v[d] = A_[16 + d] * i2; m2v[d] = A_[19 + d] * i2; }

    int sig[3]; sig[0] = 2; sig[1] = 0; sig[2] = 1;   // Q_MAT permutation
    float rv[9];
    #pragma unroll
    for (int a = 0; a < 3; ++a)
        #pragma unroll
        for (int b = 0; b < 3; ++b)
            rv[a * 3 + b] = o11[sig[a] * 3 + sig[b]];
    float ta[3], tb[3];
    #pragma unroll
    for (int a = 0; a < 3; ++a) { ta[a] = o10[sig[a]]; tb[a] = o01[sig[a]]; }

    float nn = 0.f;
    #pragma unroll
    for (int k = 0; k < 9; ++k) nn += rv[k] * rv[k];
    float invn = 1.f / fmaxf(sqrtf(nn), 1e-5f);
    float M[3][3];
    #pragma unroll
    for (int a = 0; a < 3; ++a)
        #pragma unroll
        for (int b = 0; b < 3; ++b)
            M[a][b] = rv[b * 3 + a] * invn;

    float S[3][3], V[3][3];
    #pragma unroll
    for (int a = 0; a < 3; ++a)
        #pragma unroll
        for (int b = 0; b < 3; ++b) {
            float acc = 0.f;
            #pragma unroll
            for (int k = 0; k < 3; ++k) acc += M[k][a] * M[k][b];
            S[a][b] = acc;
            V[a][b] = (a == b) ? 1.f : 0.f;
        }
    for (int sw = 0; sw < 12; ++sw) { JROT(0, 1); JROT(0, 2); JROT(1, 2); }

    float l0 = S[0][0], l1 = S[1][1], l2 = S[2][2];
    float e0x = V[0][0], e0y = V[1][0], e0z = V[2][0];
    float e1x = V[0][1], e1y = V[1][1], e1z = V[2][1];
    float e2x = V[0][2], e2y = V[1][2], e2z = V[2][2];
    float tfl;
    if (l0 < l1) { tfl=l0;l0=l1;l1=tfl; tfl=e0x;e0x=e1x;e1x=tfl; tfl=e0y;e0y=e1y;e1y=tfl; tfl=e0z;e0z=e1z;e1z=tfl; }
    if (l0 < l2) { tfl=l0;l0=l2;l2=tfl; tfl=e0x;e0x=e2x;e2x=tfl; tfl=e0y;e0y=e2y;e2y=tfl; tfl=e0z;e0z=e2z;e2z=tfl; }
    if (l1 < l2) { tfl=l1;l1=l2;l2=tfl; tfl=e1x;e1x=e2x;e2x=tfl; tfl=e1y;e1y=e2y;e2y=tfl; tfl=e1z;e1z=e2z;e2z=tfl; }

    float c2x = e0y * e1z - e0z * e1y;
    float c2y = e0z * e1x - e0x * e1z;
    float c2z = e0x * e1y - e0y * e1x;
    float cn = rsqrtf(fmaxf(c2x * c2x + c2y * c2y + c2z * c2z, 1e-30f));
    c2x *= cn; c2y *= cn; c2z *= cn;

    float u0x = M[0][0] * e0x + M[0][1] * e0y + M[0][2] * e0z;
    float u0y = M[1][0] * e0x + M[1][1] * e0y + M[1][2] * e0z;
    float u0z = M[2][0] * e0x + M[2][1] * e0y + M[2][2] * e0z;
    float un = rsqrtf(fmaxf(u0x * u0x + u0y * u0y + u0z * u0z, 1e-30f));
    u0x *= un; u0y *= un; u0z *= un;
    float u1x = M[0][0] * e1x + M[0][1] * e1y + M[0][2] * e1z;
    float u1y = M[1][0] * e1x + M[1][1] * e1y + M[1][2] * e1z;
    float u1z = M[2][0] * e1x + M[2][1] * e1y + M[2][2] * e1z;
    float dp = u0x * u1x + u0y * u1y + u0z * u1z;
    u1x -= dp * u0x; u1y -= dp * u0y; u1z -= dp * u0z;
    un = rsqrtf(fmaxf(u1x * u1x + u1y * u1y + u1z * u1z, 1e-30f));
    u1x *= un; u1y *= un; u1z *= un;
    float u2x = u0y * u1z - u0z * u1y;
    float u2y = u0z * u1x - u0x * u1z;
    float u2z = u0x * u1y - u0y * u1x;

    float R[3][3];
    R[0][0] = u0x * e0x + u1x * e1x + u2x * c2x;
    R[0][1] = u0x * e0y + u1x * e1y + u2x * c2y;
    R[0][2] = u0x * e0z + u1x * e1z + u2x * c2z;
    R[1][0] = u0y * e0x + u1y * e1x + u2y * c2x;
    R[1][1] = u0y * e0y + u1y * e1y + u2y * c2y;
    R[1][2] = u0y * e0z + u1y * e1z + u2y * c2z;
    R[2][0] = u0z * e0x + u1z * e1x + u2z * c2x;
    R[2][1] = u0z * e0y + u1z * e1y + u2z * c2y;
    R[2][2] = u0z * e0z + u1z * e1z + u2z * c2z;

    float tv[3];
    #pragma unroll
    for (int a = 0; a < 3; ++a) {
        float acc = m2v[a] + tb[a];
        #pragma unroll
        for (int b = 0; b < 3; ++b) acc -= R[a][b] * (m1v[b] + ta[b]);
        tv[a] = acc;
    }

    #pragma unroll
    for (int k = 0; k < 9; ++k) out[(long)g * 9 + k] = R[k / 3][k % 3];
    #pragma unroll
    for (int a = 0; a < 3; ++a) out[(long)GG * 9 + (long)g * 3 + a] = tv[a];
    #pragma unroll
    for (int k = 0; k < 9; ++k) out[(long)GG * 12 + (long)g * 9 + k] = rv[k];
}

extern "C" void kernel_launch(void* const* d_in, const int* in_sizes, int n_in,
                              void* d_out, int out_size, void* d_ws, size_t ws_size,
                              hipStream_t stream)
{
    const float* x00   = (const float*)d_in[0];
    const float* x10   = (const float*)d_in[1];
    const float* x01   = (const float*)d_in[2];
    const float* x11   = (const float*)d_in[3];
    const float* pos   = (const float*)d_in[4];
    const int*   gid   = (const int*)d_in[5];
    const float* gamma = (const float*)d_in[7];
    const float* beta  = (const float*)d_in[8];
    const float* lin_w = (const float*)d_in[9];
    const float* lin_b = (const float*)d_in[10];
    const float* w10   = (const float*)d_in[11];
    const float* w01   = (const float*)d_in[12];
    const float* w11   = (const float*)d_in[13];
    float* out = (float*)d_out;

    const int N = in_sizes[0] / NF;   // 262144

    // workspace layout (floats)
    float* ws = (float*)d_ws;
    float* gsum  = ws;                       // GG*64
    float* gsq   = gsum + GG * 64;           // GG*64
    float* gcnt  = gsq + GG * 64;            // GG
    float* accum = gcnt + GG;                // GG*32
    float* Aeff  = accum + GG * 32;          // GG*192
    float* Beff  = Aeff + GG * 192;          // GG*3
    float* ebp   = Beff + GG * 3;            // 2*N (planar e0,e1)

    size_t zeroBytes = (size_t)(GG * 64 * 2 + GG + GG * 32) * sizeof(float);
    hipMemsetAsync(d_ws, 0, zeroBytes, stream);

    int blocksA = (N / 64) / 4;               // 1024
    int blocksL = (N / 64) / 2;               // 2048
    int blocksD = 2 * (N / 256);              // 2048 (even: x11, odd: x10/x01)

    k_stats <<<blocksA, 256, 0, stream>>>(x00, gid, gsum, gsq, gcnt, N);
    k_prep  <<<GG, 64, 0, stream>>>(gsum, gsq, gcnt, gamma, beta, lin_w, lin_b, Aeff, Beff);
    k_logits<<<blocksL, 128, 0, stream>>>(x00, gid, pos, Aeff, Beff, ebp, accum, N);
    k_wsum  <<<blocksD, 256, 0, stream>>>(x10, x01, x11, ebp, gid, w10, w01, w11, accum, N);
    k_final <<<(GG + 63) / 64, 64, 0, stream>>>(accum, out);
}

// Round 18
// 167.981 us; speedup vs baseline: 1.4708x; 1.4708x over previous
//
#include <hip/hip_runtime.h>
#include <cstdint>
#include <cstddef>

#define GG 512
#define NF 64
#define EPSF 1e-5f

__device__ __forceinline__ void atomAddF(float* p, float v) {
    unsafeAtomicAdd(p, v);   // hardware global_atomic_add_f32
}

// async HBM->LDS DMA: per-lane global source, wave-uniform LDS base,
// lane i deposits <size>B at ldsBase + i*size. Tracked by vmcnt.
__device__ __forceinline__ void gl_lds16(const float* g, float* l) {
    __builtin_amdgcn_global_load_lds(
        (const __attribute__((address_space(1))) void*)g,
        (__attribute__((address_space(3))) void*)l, 16, 0, 0);
}
__device__ __forceinline__ void gl_lds4(const float* g, float* l) {
    __builtin_amdgcn_global_load_lds(
        (const __attribute__((address_space(1))) void*)g,
        (__attribute__((address_space(3))) void*)l, 4, 0, 0);
}

__device__ __forceinline__ void waitv(int n) {
    switch (n) {
        case 0: asm volatile("s_waitcnt vmcnt(0)" ::: "memory"); break;
        case 1: asm volatile("s_waitcnt vmcnt(1)" ::: "memory"); break;
        case 2: asm volatile("s_waitcnt vmcnt(2)" ::: "memory"); break;
        default: asm volatile("s_waitcnt vmcnt(3)" ::: "memory"); break;
    }
}

// ---------------- Pass A: per-graph sum / sumsq / count of x00 ----------------
__global__ __launch_bounds__(256) void k_stats(const float* __restrict__ x00, const int* __restrict__ gid,
                        float* __restrict__ gsum, float* __restrict__ gsq,
                        float* __restrict__ gcnt, int N)
{
    int w = (blockIdx.x * blockDim.x + threadIdx.x) >> 6;
    int lane = threadIdx.x & 63;
    long base = (long)w * 64;
    int gf = gid[base];
    int gl = gid[base + 63];
    if (gf == gl) {
        const float4* p = reinterpret_cast<const float4*>(x00 + base * NF) + lane;
        float s0=0,s1=0,s2=0,s3=0,q0=0,q1=0,q2=0,q3=0;
        #pragma unroll
        for (int k = 0; k < 16; ++k) {
            float4 v = p[k * 64];
            s0+=v.x; s1+=v.y; s2+=v.z; s3+=v.w;
            q0=fmaf(v.x,v.x,q0); q1=fmaf(v.y,v.y,q1); q2=fmaf(v.z,v.z,q2); q3=fmaf(v.w,v.w,q3);
        }
        #pragma unroll
        for (int m = 16; m < 64; m <<= 1) {
            s0+=__shfl_xor(s0,m); s1+=__shfl_xor(s1,m); s2+=__shfl_xor(s2,m); s3+=__shfl_xor(s3,m);
            q0+=__shfl_xor(q0,m); q1+=__shfl_xor(q1,m); q2+=__shfl_xor(q2,m); q3+=__shfl_xor(q3,m);
        }
        if (lane < 16) {
            float* ds = gsum + gf * NF + lane * 4;
            float* dq = gsq  + gf * NF + lane * 4;
            atomAddF(ds+0,s0); atomAddF(ds+1,s1); atomAddF(ds+2,s2); atomAddF(ds+3,s3);
            atomAddF(dq+0,q0); atomAddF(dq+1,q1); atomAddF(dq+2,q2); atomAddF(dq+3,q3);
        }
        if (lane == 0) atomAddF(&gcnt[gf], 64.0f);
    } else {
        int myg = gid[base + lane];
        int cur = gf;
        float s = 0.f, q = 0.f, cnt = 0.f;
        for (int k = 0; k < 64; ++k) {
            int g = __shfl(myg, k);
            if (g != cur) {
                atomAddF(&gsum[cur * NF + lane], s);
                atomAddF(&gsq [cur * NF + lane], q);
                if (lane == 0) atomAddF(&gcnt[cur], cnt);
                s = q = cnt = 0.f; cur = g;
            }
            float v = x00[(base + k) * NF + lane];
            s += v; q = fmaf(v, v, q); cnt += 1.f;
        }
        atomAddF(&gsum[cur * NF + lane], s);
        atomAddF(&gsq [cur * NF + lane], q);
        if (lane == 0) atomAddF(&gcnt[cur], cnt);
    }
}

// ------------- Per-graph effective affine weights for logits ------------------
__global__ void k_prep(const float* __restrict__ gsum, const float* __restrict__ gsq,
                       const float* __restrict__ gcnt,
                       const float* __restrict__ gamma, const float* __restrict__ beta,
                       const float* __restrict__ lin_w, const float* __restrict__ lin_b,
                       float* __restrict__ Aeff, float* __restrict__ Beff)
{
    int g = blockIdx.x;
    int c = threadIdx.x;           // 64 threads = 1 wave
    float cnt = fmaxf(gcnt[g], 1.f);
    float mean = gsum[g * NF + c] / cnt;
    float var  = gsq [g * NF + c] / cnt - mean * mean;
    float rs = rsqrtf(var + EPSF);
    float ga = gamma[c], be = beta[c];
    #pragma unroll
    for (int j = 0; j < 3; ++j) {
        float wv = lin_w[j * NF + c];
        Aeff[((long)g * 3 + j) * NF + c] = rs * ga * wv;
        float term = (be - mean * rs * ga) * wv;
        #pragma unroll
        for (int m = 32; m; m >>= 1) term += __shfl_xor(term, m);
        if (c == 0) Beff[g * 3 + j] = term + lin_b[j];
    }
}

// --------- Pass B: logits -> e (no max-shift), pos-weighted sums, e-sums ------
__global__ __launch_bounds__(128) void k_logits(const float* __restrict__ x00, const int* __restrict__ gid,
                         const float* __restrict__ pos,
                         const float* __restrict__ Aeff, const float* __restrict__ Beff,
                         float* __restrict__ ebp, float* __restrict__ accum, int N)
{
    __shared__ float T2[2][64 * 68];
    int wid = threadIdx.x >> 6;
    int lane = threadIdx.x & 63;
    long chunk = (long)blockIdx.x * 2 + wid;
    long base = chunk * 64;
    float* T = T2[wid];

    const float* src = x00 + base * NF;
    #pragma unroll
    for (int k = 0; k < 16; ++k) {
        int fl = k * 256 + lane * 4;
        float4 v = *reinterpret_cast<const float4*>(src + fl);
        int n = fl >> 6, c = fl & 63;
        *reinterpret_cast<float4*>(&T[n * 68 + c]) = v;
    }
    __syncthreads();

    int gf = gid[base], gl = gid[base + 63];
    float l0, l1, l2;
    int g_l;
    if (gf == gl) {
        g_l = gf;
        const float* ap = Aeff + (size_t)gf * 192;
        float a0a=0,a0b=0,a1a=0,a1b=0,a2a=0,a2b=0;
        #pragma unroll
        for (int t = 0; t < 16; ++t) {
            float4 xv = *reinterpret_cast<const float4*>(&T[lane * 68 + 4 * t]);
            float4 w0 = *reinterpret_cast<const float4*>(ap + 4 * t);
            float4 w1 = *reinterpret_cast<const float4*>(ap + 64 + 4 * t);
            float4 w2 = *reinterpret_cast<const float4*>(ap + 128 + 4 * t);
            a0a = fmaf(xv.x,w0.x,fmaf(xv.y,w0.y,a0a)); a0b = fmaf(xv.z,w0.z,fmaf(xv.w,w0.w,a0b));
            a1a = fmaf(xv.x,w1.x,fmaf(xv.y,w1.y,a1a)); a1b = fmaf(xv.z,w1.z,fmaf(xv.w,w1.w,a1b));
            a2a = fmaf(xv.x,w2.x,fmaf(xv.y,w2.y,a2a)); a2b = fmaf(xv.z,w2.z,fmaf(xv.w,w2.w,a2b));
        }
        l0 = a0a + a0b + Beff[gf*3+0];
        l1 = a1a + a1b + Beff[gf*3+1];
        l2 = a2a + a2b + Beff[gf*3+2];
    } else {
        g_l = gid[base + lane];
        const float* ap = Aeff + (size_t)g_l * 192;
        float a0=0,a1=0,a2=0;
        #pragma unroll
        for (int t = 0; t < 16; ++t) {
            float4 xv = *reinterpret_cast<const float4*>(&T[lane * 68 + 4 * t]);
            float4 w0 = *reinterpret_cast<const float4*>(ap + 4 * t);
            float4 w1 = *reinterpret_cast<const float4*>(ap + 64 + 4 * t);
            float4 w2 = *reinterpret_cast<const float4*>(ap + 128 + 4 * t);
            a0 = fmaf(xv.x,w0.x,fmaf(xv.y,w0.y,fmaf(xv.z,w0.z,fmaf(xv.w,w0.w,a0))));
            a1 = fmaf(xv.x,w1.x,fmaf(xv.y,w1.y,fmaf(xv.z,w1.z,fmaf(xv.w,w1.w,a1))));
            a2 = fmaf(xv.x,w2.x,fmaf(xv.y,w2.y,fmaf(xv.z,w2.z,fmaf(xv.w,w2.w,a2))));
        }
        l0 = a0 + Beff[g_l*3+0];
        l1 = a1 + Beff[g_l*3+1];
        l2 = a2 + Beff[g_l*3+2];
    }
    float e0 = expf(l0), e1 = expf(l1), e2 = expf(l2);
    long node = base + lane;
    ebp[node]            = e0;
    ebp[(long)N + node]  = e1;

    const float* pp = pos + node * 6;
    float2 v01 = *reinterpret_cast<const float2*>(pp);
    float2 v23 = *reinterpret_cast<const float2*>(pp + 2);
    float2 v45 = *reinterpret_cast<const float2*>(pp + 4);
    float p0 = v01.x*e2, p1 = v01.y*e2, p2 = v23.x*e2, p3 = v23.y*e2, p4 = v45.x*e2, p5 = v45.y*e2;
    if (gf == gl) {
        #pragma unroll
        for (int m = 1; m < 64; m <<= 1) {
            e0+=__shfl_xor(e0,m); e1+=__shfl_xor(e1,m); e2+=__shfl_xor(e2,m);
            p0+=__shfl_xor(p0,m); p1+=__shfl_xor(p1,m); p2+=__shfl_xor(p2,m);
            p3+=__shfl_xor(p3,m); p4+=__shfl_xor(p4,m); p5+=__shfl_xor(p5,m);
        }
        if (lane == 0) {
            float* dst = accum + (long)gf * 32;
            atomAddF(dst+16,p0); atomAddF(dst+17,p1); atomAddF(dst+18,p2);
            atomAddF(dst+19,p3); atomAddF(dst+20,p4); atomAddF(dst+21,p5);
            atomAddF(dst+22,e0); atomAddF(dst+23,e1); atomAddF(dst+24,e2);
        }
    } else {
        float* dst = accum + (long)g_l * 32;
        atomAddF(dst+16,p0); atomAddF(dst+17,p1); atomAddF(dst+18,p2);
        atomAddF(dst+19,p3); atomAddF(dst+20,p4); atomAddF(dst+21,p5);
        atomAddF(dst+22,e0); atomAddF(dst+23,e1); atomAddF(dst+24,e2);
    }
}

// ---- Pass D (merged): even blocks -> x11, odd blocks -> x10/x01.
// 16 tiles of 16 nodes; 3-deep LDS ring filled by async global_load_lds;
// prefetch 2 tiles ahead; counted s_waitcnt vmcnt(N) + RAW s_barrier so the
// next tiles' DMAs stay in flight ACROSS barriers (T3/T4). e-values ride in
// the DMA stream (no vmem ops in compute on the hot path).
__global__ __launch_bounds__(256) void k_wsum(const float* __restrict__ x10,
        const float* __restrict__ x01, const float* __restrict__ x11,
        const float* __restrict__ ebp, const int* __restrict__ gid,
        const float* __restrict__ w10, const float* __restrict__ w01,
        const float* __restrict__ w11, float* __restrict__ accum, int N)
{
    __shared__ float SMEM[7104];          // x11: 3*2320 + 144 = 7104 floats
    const int tid = threadIdx.x;
    const int wid = tid >> 6;
    const int lane = tid & 63;
    const int T = 16;

    if ((blockIdx.x & 1) == 0) {
        // ---------------- x11 (16-node tiles: 2304 data + 16 e) ----------------
        const long blkBase = (long)(blockIdx.x >> 1) * 256;
        float* F = SMEM + 6960;            // 144

        float w[16];
        #pragma unroll
        for (int c = 0; c < 16; ++c) w[c] = w11[c];

        const bool act = tid < 144;
        const int n1 = (act ? tid : 0) / 9;
        const int d1 = (act ? tid : 0) - 9 * ((act ? tid : 0) / 9);
        const int Sw = (wid == 0 || wid == 3) ? 3 : 2;

        float acc1 = 0.f;
        int cur = gid[blkBase];
        bool dirty = false;

        auto flush = [&]() {
            if (dirty) {
                if (act) F[tid] = acc1;
                __syncthreads();
                if (tid < 9) {
                    float s = 0.f;
                    #pragma unroll
                    for (int n = 0; n < 16; ++n) s += F[n * 9 + tid];
                    atomAddF(accum + (long)cur * 32 + 6 + tid, s);
                }
                __syncthreads();
                acc1 = 0.f;
                dirty = false;
            }
        };

        auto issueT = [&](int t) {
            const long tb = blkBase + (long)t * 16;
            const float* src = x11 + tb * 144;
            float* dst = SMEM + (t % 3) * 2320;
            if (wid == 0) {
                gl_lds16(src + 0 * 256 + lane * 4, dst + 0 * 256);
                gl_lds16(src + 1 * 256 + lane * 4, dst + 1 * 256);
                gl_lds16(src + 8 * 256 + lane * 4, dst + 8 * 256);
            } else if (wid == 1) {
                gl_lds16(src + 2 * 256 + lane * 4, dst + 2 * 256);
                gl_lds16(src + 3 * 256 + lane * 4, dst + 3 * 256);
            } else if (wid == 2) {
                gl_lds16(src + 4 * 256 + lane * 4, dst + 4 * 256);
                gl_lds16(src + 5 * 256 + lane * 4, dst + 5 * 256);
            } else {
                gl_lds16(src + 6 * 256 + lane * 4, dst + 6 * 256);
                gl_lds16(src + 7 * 256 + lane * 4, dst + 7 * 256);
                if (lane < 16) gl_lds4(ebp + tb + lane, dst + 2304);
            }
        };

        issueT(0);
        issueT(1);

        for (int t = 0; t < T; ++t) {
            waitv(t == T - 1 ? 0 : Sw);            // tile t landed; t+1 stays in flight
            __builtin_amdgcn_s_barrier();
            __builtin_amdgcn_sched_barrier(0);
            if (t + 2 < T) issueT(t + 2);          // into slot just freed (all read it)
            const float* B = SMEM + (t % 3) * 2320;
            long tb = blkBase + (long)t * 16;
            int gf = gid[tb], gl = gid[tb + 15];
            float y1 = 0.f, ev = 0.f;
            if (act) {
                ev = B[2304 + n1];
                #pragma unroll
                for (int c = 0; c < 16; ++c) y1 = fmaf(w[c], B[n1 * 144 + c * 9 + d1], y1);
            }
            if (gf == gl) {
                if (gf != cur) { flush(); cur = gf; }
                if (act) acc1 = fmaf(ev, y1, acc1);
                dirty = true;
            } else {
                flush();
                if (act) atomAddF(accum + (long)gid[tb + n1] * 32 + 6 + d1, ev * y1);
                cur = gl;
            }
        }
        flush();
    } else {
        // ---------------- x10 / x01 (16-node tiles: 1536 data + 16 e) ----------
        const long blkBase = (long)(blockIdx.x >> 1) * 256;
        float* F = SMEM + 4656;            // 96

        const bool act = tid < 96;
        const int arr = (tid < 48) ? 0 : 1;
        const int rem = (act ? (tid - 48 * arr) : 0);
        const int nn = rem / 3;
        const int dd = rem - 3 * (rem / 3);
        const int Sw = (wid == 3) ? 1 : 2;

        float wsel[16];
        #pragma unroll
        for (int c = 0; c < 16; ++c) wsel[c] = arr ? w01[c] : w10[c];

        float acc = 0.f;
        int cur = gid[blkBase];
        bool dirty = false;

        auto flush = [&]() {
            if (dirty) {
                if (act) F[tid] = acc;
                __syncthreads();
                if (tid < 6) {
                    int a = tid / 3, d = tid - 3 * a;
                    float s = 0.f;
                    #pragma unroll
                    for (int n = 0; n < 16; ++n) s += F[a * 48 + n * 3 + d];
                    atomAddF(accum + (long)cur * 32 + a * 3 + d, s);
                }
                __syncthreads();
                acc = 0.f;
                dirty = false;
            }
        };

        auto issueT = [&](int t) {
            const long tb = blkBase + (long)t * 16;
            const long tb48 = tb * 48;
            float* dst = SMEM + (t % 3) * 1552;
            if (wid == 0) {
                gl_lds16(x10 + tb48 + 0 * 256 + lane * 4, dst + 0 * 256);
                gl_lds16(x10 + tb48 + 1 * 256 + lane * 4, dst + 1 * 256);
            } else if (wid == 1) {
                gl_lds16(x10 + tb48 + 2 * 256 + lane * 4, dst + 2 * 256);
                gl_lds16(x01 + tb48 + 0 * 256 + lane * 4, dst + 768);
            } else if (wid == 2) {
                gl_lds16(x01 + tb48 + 1 * 256 + lane * 4, dst + 768 + 256);
                gl_lds16(x01 + tb48 + 2 * 256 + lane * 4, dst + 768 + 512);
            } else {
                if (lane < 16) gl_lds4(ebp + (long)N + tb + lane, dst + 1536);
            }
        };

        issueT(0);
        issueT(1);

        for (int t = 0; t < T; ++t) {
            waitv(t == T - 1 ? 0 : Sw);
            __builtin_amdgcn_s_barrier();
            __builtin_amdgcn_sched_barrier(0);
            if (t + 2 < T) issueT(t + 2);
            const float* D = SMEM + (t % 3) * 1552;
            const float* Bx = D + arr * 768;
            long tb = blkBase + (long)t * 16;
            int gf = gid[tb], gl = gid[tb + 15];
            float y = 0.f, ev = 0.f;
            if (act) {
                ev = D[1536 + nn];
                #pragma unroll
                for (int c = 0; c < 16; ++c) y = fmaf(wsel[c], Bx[nn * 48 + c * 3 + dd], y);
            }
            if (gf == gl) {
                if (gf != cur) { flush(); cur = gf; }
                if (act) acc = fmaf(ev, y, acc);
                dirty = true;
            } else {
                flush();
                if (act) atomAddF(accum + (long)gid[tb + nn] * 32 + arr * 3 + dd, ev * y);
                cur = gl;
            }
        }
        flush();
    }
}

// --------------------------- Pass E: per-graph epilogue -----------------------
#define JROT(p, q) do { \
    float apq_ = S[p][q]; \
    if (fabsf(apq_) > 1e-20f) { \
        float app_ = S[p][p], aqq_ = S[q][q]; \
        float tau_ = (aqq_ - app_) / (2.0f * apq_); \
        float tt_ = copysignf(1.0f, tau_) / (fabsf(tau_) + sqrtf(1.0f + tau_ * tau_)); \
        float cc_ = 1.0f / sqrtf(1.0f + tt_ * tt_); \
        float ssn_ = tt_ * cc_; \
        _Pragma("unroll") for (int kk = 0; kk < 3; ++kk) { \
            float skp = S[kk][p], skq = S[kk][q]; \
            S[kk][p] = cc_ * skp - ssn_ * skq; S[kk][q] = ssn_ * skp + cc_ * skq; } \
        _Pragma("unroll") for (int kk = 0; kk < 3; ++kk) { \
            float spk = S[p][kk], sqk = S[q][kk]; \
            S[p][kk] = cc_ * spk - ssn_ * sqk; S[q][kk] = ssn_ * spk + cc_ * sqk; } \
        _Pragma("unroll") for (int kk = 0; kk < 3; ++kk) { \
            float vkp = V[kk][p], vkq = V[kk][q]; \
            V[kk][p] = cc_ * vkp - ssn_ * vkq; V[kk][q] = ssn_ * vkp + cc_ * vkq; } \
    } \
} while (0)

__global__ void k_final(const float* __restrict__ accum, float* __restrict__ out)
{
    int g = blockIdx.x * blockDim.x + threadIdx.x;
    if (g >= GG) return;
    const float* A_ = accum + (long)g * 32;
    float i0 = 1.f / A_[22], i1 = 1.f / A_[23], i2 = 1.f / A_[24];

    float o10[3], o01[3], o11[9];
    #pragma unroll
    for (int d = 0; d < 3; ++d) { o10[d] = A_[d] * i1; o01[d] = A_[3 + d] * i1; }
    #pragma unroll
    for (int d = 0; d < 9; ++d) o11[d] = A_[6 + d] * i0;

    float m1v[3], m2v[3];
    #pragma unroll
    for (int d = 0; d < 3; ++d) { m1v[d] = A_[16 + d] * i2; m2v[d] = A_[19 + d] * i2; }

    int sig[3]; sig[0] = 2; sig[1] = 0; sig[2] = 1;   // Q_MAT permutation
    float rv[9];
    #pragma unroll
    for (int a = 0; a < 3; ++a)
        #pragma unroll
        for (int b = 0; b < 3; ++b)
            rv[a * 3 + b] = o11[sig[a] * 3 + sig[b]];
    float ta[3], tb[3];
    #pragma unroll
    for (int a = 0; a < 3; ++a) { ta[a] = o10[sig[a]]; tb[a] = o01[sig[a]]; }

    float nn = 0.f;
    #pragma unroll
    for (int k = 0; k < 9; ++k) nn += rv[k] * rv[k];
    float invn = 1.f / fmaxf(sqrtf(nn), 1e-5f);
    float M[3][3];
    #pragma unroll
    for (int a = 0; a < 3; ++a)
        #pragma unroll
        for (int b = 0; b < 3; ++b)
            M[a][b] = rv[b * 3 + a] * invn;

    float S[3][3], V[3][3];
    #pragma unroll
    for (int a = 0; a < 3; ++a)
        #pragma unroll
        for (int b = 0; b < 3; ++b) {
            float acc = 0.f;
            #pragma unroll
            for (int k = 0; k < 3; ++k) acc += M[k][a] * M[k][b];
            S[a][b] = acc;
            V[a][b] = (a == b) ? 1.f : 0.f;
        }
    for (int sw = 0; sw < 12; ++sw) { JROT(0, 1); JROT(0, 2); JROT(1, 2); }

    float l0 = S[0][0], l1 = S[1][1], l2 = S[2][2];
    float e0x = V[0][0], e0y = V[1][0], e0z = V[2][0];
    float e1x = V[0][1], e1y = V[1][1], e1z = V[2][1];
    float e2x = V[0][2], e2y = V[1][2], e2z = V[2][2];
    float tfl;
    if (l0 < l1) { tfl=l0;l0=l1;l1=tfl; tfl=e0x;e0x=e1x;e1x=tfl; tfl=e0y;e0y=e1y;e1y=tfl; tfl=e0z;e0z=e1z;e1z=tfl; }
    if (l0 < l2) { tfl=l0;l0=l2;l2=tfl; tfl=e0x;e0x=e2x;e2x=tfl; tfl=e0y;e0y=e2y;e2y=tfl; tfl=e0z;e0z=e2z;e2z=tfl; }
    if (l1 < l2) { tfl=l1;l1=l2;l2=tfl; tfl=e1x;e1x=e2x;e2x=tfl; tfl=e1y;e1y=e2y;e2y=tfl; tfl=e1z;e1z=e2z;e2z=tfl; }

    float c2x = e0y * e1z - e0z * e1y;
    float c2y = e0z * e1x - e0x * e1z;
    float c2z = e0x * e1y - e0y * e1x;
    float cn = rsqrtf(fmaxf(c2x * c2x + c2y * c2y + c2z * c2z, 1e-30f));
    c2x *= cn; c2y *= cn; c2z *= cn;

    float u0x = M[0][0] * e0x + M[0][1] * e0y + M[0][2] * e0z;
    float u0y = M[1][0] * e0x + M[1][1] * e0y + M[1][2] * e0z;
    float u0z = M[2][0] * e0x + M[2][1] * e0y + M[2][2] * e0z;
    float un = rsqrtf(fmaxf(u0x * u0x + u0y * u0y + u0z * u0z, 1e-30f));
    u0x *= un; u0y *= un; u0z *= un;
    float u1x = M[0][0] * e1x + M[0][1] * e1y + M[0][2] * e1z;
    float u1y = M[1][0] * e1x + M[1][1] * e1y + M[1][2] * e1z;
    float u1z = M[2][0] * e1x + M[2][1] * e1y + M[2][2] * e1z;
    float dp = u0x * u1x + u0y * u1y + u0z * u1z;
    u1x -= dp * u0x; u1y -= dp * u0y; u1z -= dp * u0z;
    un = rsqrtf(fmaxf(u1x * u1x + u1y * u1y + u1z * u1z, 1e-30f));
    u1x *= un; u1y *= un; u1z *= un;
    float u2x = u0y * u1z - u0z * u1y;
    float u2y = u0z * u1x - u0x * u1z;
    float u2z = u0x * u1y - u0y * u1x;

    float R[3][3];
    R[0][0] = u0x * e0x + u1x * e1x + u2x * c2x;
    R[0][1] = u0x * e0y + u1x * e1y + u2x * c2y;
    R[0][2] = u0x * e0z + u1x * e1z + u2x * c2z;
    R[1][0] = u0y * e0x + u1y * e1x + u2y * c2x;
    R[1][1] = u0y * e0y + u1y * e1y + u2y * c2y;
    R[1][2] = u0y * e0z + u1y * e1z + u2y * c2z;
    R[2][0] = u0z * e0x + u1z * e1x + u2z * c2x;
    R[2][1] = u0z * e0y + u1z * e1y + u2z * c2y;
    R[2][2] = u0z * e0z + u1z * e1z + u2z * c2z;

    float tv[3];
    #pragma unroll
    for (int a = 0; a < 3; ++a) {
        float acc = m2v[a] + tb[a];
        #pragma unroll
        for (int b = 0; b < 3; ++b) acc -= R[a][b] * (m1v[b] + ta[b]);
        tv[a] = acc;
    }

    #pragma unroll
    for (int k = 0; k < 9; ++k) out[(long)g * 9 + k] = R[k / 3][k % 3];
    #pragma unroll
    for (int a = 0; a < 3; ++a) out[(long)GG * 9 + (long)g * 3 + a] = tv[a];
    #pragma unroll
    for (int k = 0; k < 9; ++k) out[(long)GG * 12 + (long)g * 9 + k] = rv[k];
}

extern "C" void kernel_launch(void* const* d_in, const int* in_sizes, int n_in,
                              void* d_out, int out_size, void* d_ws, size_t ws_size,
                              hipStream_t stream)
{
    const float* x00   = (const float*)d_in[0];
    const float* x10   = (const float*)d_in[1];
    const float* x01   = (const float*)d_in[2];
    const float* x11   = (const float*)d_in[3];
    const float* pos   = (const float*)d_in[4];
    const int*   gid   = (const int*)d_in[5];
    const float* gamma = (const float*)d_in[7];
    const float* beta  = (const float*)d_in[8];
    const float* lin_w = (const float*)d_in[9];
    const float* lin_b = (const float*)d_in[10];
    const float* w10   = (const float*)d_in[11];
    const float* w01   = (const float*)d_in[12];
    const float* w11   = (const float*)d_in[13];
    float* out = (float*)d_out;

    const int N = in_sizes[0] / NF;   // 262144

    // workspace layout (floats)
    float* ws = (float*)d_ws;
    float* gsum  = ws;                       // GG*64
    float* gsq   = gsum + GG * 64;           // GG*64
    float* gcnt  = gsq + GG * 64;            // GG
    float* accum = gcnt + GG;                // GG*32
    float* Aeff  = accum + GG * 32;          // GG*192
    float* Beff  = Aeff + GG * 192;          // GG*3
    float* ebp   = Beff + GG * 3;            // 2*N (planar e0,e1)

    size_t zeroBytes = (size_t)(GG * 64 * 2 + GG + GG * 32) * sizeof(float);
    hipMemsetAsync(d_ws, 0, zeroBytes, stream);

    int blocksA = (N / 64) / 4;               // 1024
    int blocksL = (N / 64) / 2;               // 2048
    int blocksD = 2 * (N / 256);              // 2048 (even: x11, odd: x10/x01)

    k_stats <<<blocksA, 256, 0, stream>>>(x00, gid, gsum, gsq, gcnt, N);
    k_prep  <<<GG, 64, 0, stream>>>(gsum, gsq, gcnt, gamma, beta, lin_w, lin_b, Aeff, Beff);
    k_logits<<<blocksL, 128, 0, stream>>>(x00, gid, pos, Aeff, Beff, ebp, accum, N);
    k_wsum  <<<blocksD, 256, 0, stream>>>(x10, x01, x11, ebp, gid, w10, w01, w11, accum, N);
    k_final <<<(GG + 63) / 64, 64, 0, stream>>>(accum, out);
}